// Round 19
// baseline (217.267 us; speedup 1.0000x reference)
//
#include <hip/hip_runtime.h>
#include <hip/hip_bf16.h>

typedef __attribute__((ext_vector_type(8))) short short8;
typedef __attribute__((ext_vector_type(4))) float f32x4;
typedef __attribute__((ext_vector_type(4))) unsigned uint4v;

#define NMODEL 24
#define DIN    495
#define KP     512
#define HID    64
#define NLAY   5

__device__ __forceinline__ short bf16r(float f) {
    unsigned u = __float_as_uint(f);
    u += 0x7fffu + ((u >> 16) & 1u);          // round-to-nearest-even
    return (short)(u >> 16);
}
__device__ __forceinline__ float bf16f(short s) {
    return __uint_as_float(((unsigned)(unsigned short)s) << 16);
}
// packed f32->bf16: one VALU op for two elements (gfx950 v_cvt_pk_bf16_f32)
__device__ __forceinline__ unsigned pkbf16(float lo, float hi) {
    unsigned r;
    asm("v_cvt_pk_bf16_f32 %0, %1, %2" : "=v"(r) : "v"(lo), "v"(hi));
    return r;
}
// pack two f32x4 accumulator fragments into one MFMA B-fragment (short8)
__device__ __forceinline__ short8 pack2(f32x4 a, f32x4 b) {
    uint4v w;
    w[0] = pkbf16(a[0], a[1]);
    w[1] = pkbf16(a[2], a[3]);
    w[2] = pkbf16(b[0], b[1]);
    w[3] = pkbf16(b[2], b[3]);
    return __builtin_bit_cast(short8, w);
}

struct __attribute__((packed, aligned(4))) f4a { float v[4]; };

// ---------------------------------------------------------------------------
// Weight pre-conversion to bf16 in MFMA-fragment-friendly layouts.
//   wib[m][kb][hout][t]  = W_in[m][kb*8+t][hout]          (k padded 495->512)
//   whb[m][l][kb][hout][t] = W_h[m][l][pi(kb,t)][hout]    (pi bakes the C->B
//     lane-group relabeling of the hidden-in axis)
// ---------------------------------------------------------------------------
__global__ void dg_convert(const float* __restrict__ W_in,
                           const float* __restrict__ W_h,
                           short* __restrict__ wib, short* __restrict__ whb) {
    int idx = blockIdx.x * 256 + threadIdx.x;
    if (idx < NMODEL * 64 * HID * 8) {
        int t    = idx & 7;
        int hout = (idx >> 3) & 63;
        int kb   = (idx >> 9) & 63;
        int m    = idx >> 15;
        int k    = kb * 8 + t;
        float v  = (k < DIN) ? W_in[((size_t)m * DIN + k) * HID + hout] : 0.f;
        wib[idx] = bf16r(v);
    }
    if (idx < NMODEL * NLAY * 8 * HID * 8) {
        int t    = idx & 7;
        int hout = (idx >> 3) & 63;
        int kb   = (idx >> 9) & 7;     // kb = 4*s + g
        int ml   = idx >> 12;          // m*5 + l
        int pk   = 16 * (2 * (kb >> 2) + (t >> 2)) + 4 * (kb & 3) + (t & 3);
        float v  = W_h[((size_t)ml * HID + pk) * HID + hout];
        whb[idx] = bf16r(v);
    }
}

// ---------------------------------------------------------------------------
// Fused kernel (r18 base + ONE lever): paired-step load grouping pinned by
// sched_barrier(0). Each step loads TWO clusters' weights (skt/skt+1, or
// hidden s0+s1) into separately-named registers BEFORE a full scheduling
// fence, then runs both MFMA clusters. The fence forbids the compiler from
// re-sinking the second cluster's loads (r5's failure); the backend's own
// per-use COUNTED waitcnt then leaves cluster B's loads in flight during
// cluster A's MFMAs — depth-1 latency hiding with zero inline-asm loads
// (no scratch demotion, no positional-vmcnt fragility: r6/r9/r16/r17's
// failures). FP order bit-identical to r18 (absmax must be 5.859e-3).
// 64KB LDS -> 2 blocks/CU -> 16 waves/CU (4/SIMD). setprio per cluster.
// ---------------------------------------------------------------------------
__global__ __launch_bounds__(512, 4) void dg_main(
    const float* __restrict__ x,
    const short* __restrict__ wib, const short* __restrict__ whb,
    const float* __restrict__ b_in, const float* __restrict__ b_h,
    const float* __restrict__ W_out, const float* __restrict__ b_out,
    float* __restrict__ out) {

    __shared__ short xs[64 * KP];            // 64 KB

    const int tid  = threadIdx.x;
    const int lane = tid & 63;
    const int w    = tid >> 6;               // wave 0..7
    const int lrow = lane & 15;
    const int g    = lane >> 4;              // lane group 0..3
    const int rowbase = blockIdx.x * 64;
    const int pair = w >> 1;                 // 0..3: model group
    const int hf   = w & 1;                  // row half within the tile
    const int rbase = hf * 32;

    // ---- stage x tile -> LDS as bf16, swizzled, zero-padded k>=495 ----
    for (int i = 0; i < 8; ++i) {
        int r  = i * 8 + w;
        int k0 = lane * 8;
        const float* xr = x + (size_t)(rowbase + r) * DIN + k0;
        uint4v vw;
        if (k0 + 8 <= DIN) {                 // lanes 0..60: fast vector path
            f4a a = *(const f4a*)xr;
            f4a b = *(const f4a*)(xr + 4);
            vw[0] = pkbf16(a.v[0], a.v[1]);
            vw[1] = pkbf16(a.v[2], a.v[3]);
            vw[2] = pkbf16(b.v[0], b.v[1]);
            vw[3] = pkbf16(b.v[2], b.v[3]);
        } else {                             // lanes 61..63: guarded tail
            float f[8];
#pragma unroll
            for (int j = 0; j < 8; ++j) f[j] = (k0 + j < DIN) ? xr[j] : 0.f;
            vw[0] = pkbf16(f[0], f[1]);
            vw[1] = pkbf16(f[2], f[3]);
            vw[2] = pkbf16(f[4], f[5]);
            vw[3] = pkbf16(f[6], f[7]);
        }
        int byte = (r * (KP * 2) + k0 * 2) ^ ((r & 7) << 4);
        *(short8*)((char*)xs + byte) = __builtin_bit_cast(short8, vw);
    }
    __syncthreads();

    // ---- 6 models per wave (paired across row halves), no further sync ----
#pragma unroll 1
    for (int mi = 0; mi < 6; ++mi) {
        const int m = pair * 6 + mi;

        // ---------------- input projection: C[hout 64][row 32], K = 512
        f32x4 acc[4][2];                      // [icf(hout/16)][rf(row/16)]
#pragma unroll
        for (int a = 0; a < 4; ++a)
#pragma unroll
            for (int b = 0; b < 2; ++b) acc[a][b] = (f32x4)0.0f;

        const short8* wA = (const short8*)wib + (size_t)m * 64 * 64;
#pragma unroll 1
        for (int sp = 0; sp < 8; ++sp) {
            const int se = 2 * sp, so = 2 * sp + 1;
            short8 afrA[4], afrB[4], bfrA[2], bfrB[2];
#pragma unroll
            for (int icf = 0; icf < 4; ++icf)
                afrA[icf] = wA[(size_t)(se * 4 + g) * 64 + icf * 16 + lrow];
#pragma unroll
            for (int icf = 0; icf < 4; ++icf)
                afrB[icf] = wA[(size_t)(so * 4 + g) * 64 + icf * 16 + lrow];
#pragma unroll
            for (int rf = 0; rf < 2; ++rf) {
                int r = rbase + rf * 16 + lrow;
                int byteA = (r * (KP * 2) + se * 64 + g * 16) ^ ((r & 7) << 4);
                int byteB = (r * (KP * 2) + so * 64 + g * 16) ^ ((r & 7) << 4);
                bfrA[rf] = *(const short8*)((const char*)xs + byteA);
                bfrB[rf] = *(const short8*)((const char*)xs + byteB);
            }
            __builtin_amdgcn_sched_barrier(0);   // pin: all loads issued above
            __builtin_amdgcn_s_setprio(1);
#pragma unroll
            for (int icf = 0; icf < 4; ++icf)
#pragma unroll
                for (int rf = 0; rf < 2; ++rf)
                    acc[icf][rf] = __builtin_amdgcn_mfma_f32_16x16x32_bf16(
                        afrA[icf], bfrA[rf], acc[icf][rf], 0, 0, 0);
            __builtin_amdgcn_s_setprio(0);
            __builtin_amdgcn_sched_barrier(0);   // keep B strictly after A
            __builtin_amdgcn_s_setprio(1);
#pragma unroll
            for (int icf = 0; icf < 4; ++icf)
#pragma unroll
                for (int rf = 0; rf < 2; ++rf)
                    acc[icf][rf] = __builtin_amdgcn_mfma_f32_16x16x32_bf16(
                        afrB[icf], bfrB[rf], acc[icf][rf], 0, 0, 0);
            __builtin_amdgcn_s_setprio(0);
        }

        // + b_in  (h0 is NOT relu'd)
        const float* bi = b_in + m * HID;
#pragma unroll
        for (int icf = 0; icf < 4; ++icf) {
            f32x4 bv = *(const f32x4*)(bi + icf * 16 + g * 4);
#pragma unroll
            for (int rf = 0; rf < 2; ++rf) acc[icf][rf] += bv;
        }

        // pack h0 into B-fragments (also kept for the residual)
        short8 h0b[2][2];                     // [s][rf]
#pragma unroll
        for (int s = 0; s < 2; ++s)
#pragma unroll
            for (int rf = 0; rf < 2; ++rf)
                h0b[s][rf] = pack2(acc[2 * s][rf], acc[2 * s + 1][rf]);

        // ---------------- 5 hidden layers, all in registers
        const short8* wH = (const short8*)whb + (size_t)m * NLAY * 8 * 64;
        short8 hc[2][2];
#pragma unroll
        for (int s = 0; s < 2; ++s)
#pragma unroll
            for (int rf = 0; rf < 2; ++rf) hc[s][rf] = h0b[s][rf];

        f32x4 hacc[4][2];
#pragma unroll 1
        for (int l = 0; l < NLAY; ++l) {
#pragma unroll
            for (int a = 0; a < 4; ++a)
#pragma unroll
                for (int b = 0; b < 2; ++b) hacc[a][b] = (f32x4)0.0f;
            // load BOTH s-halves' weights before the fence
            short8 afrA[4], afrB[4];
#pragma unroll
            for (int icf = 0; icf < 4; ++icf)
                afrA[icf] = wH[(size_t)(l * 8 + g) * 64 + icf * 16 + lrow];
#pragma unroll
            for (int icf = 0; icf < 4; ++icf)
                afrB[icf] = wH[(size_t)(l * 8 + 4 + g) * 64 + icf * 16 + lrow];
            __builtin_amdgcn_sched_barrier(0);
            __builtin_amdgcn_s_setprio(1);
#pragma unroll
            for (int icf = 0; icf < 4; ++icf)
#pragma unroll
                for (int rf = 0; rf < 2; ++rf)
                    hacc[icf][rf] = __builtin_amdgcn_mfma_f32_16x16x32_bf16(
                        afrA[icf], hc[0][rf], hacc[icf][rf], 0, 0, 0);
            __builtin_amdgcn_s_setprio(0);
            __builtin_amdgcn_sched_barrier(0);
            __builtin_amdgcn_s_setprio(1);
#pragma unroll
            for (int icf = 0; icf < 4; ++icf)
#pragma unroll
                for (int rf = 0; rf < 2; ++rf)
                    hacc[icf][rf] = __builtin_amdgcn_mfma_f32_16x16x32_bf16(
                        afrB[icf], hc[1][rf], hacc[icf][rf], 0, 0, 0);
            __builtin_amdgcn_s_setprio(0);
            // bias + relu
            const float* bh = b_h + (size_t)(m * NLAY + l) * HID;
#pragma unroll
            for (int icf = 0; icf < 4; ++icf) {
                f32x4 bv = *(const f32x4*)(bh + icf * 16 + g * 4);
#pragma unroll
                for (int rf = 0; rf < 2; ++rf)
#pragma unroll
                    for (int j = 0; j < 4; ++j)
                        hacc[icf][rf][j] = fmaxf(hacc[icf][rf][j] + bv[j], 0.f);
            }
            if (l != NLAY - 1) {
#pragma unroll
                for (int s = 0; s < 2; ++s)
#pragma unroll
                    for (int rf = 0; rf < 2; ++rf)
                        hc[s][rf] = pack2(hacc[2 * s][rf], hacc[2 * s + 1][rf]);
            }
        }

        // ---------------- residual: h += h0 (bf16-rounded h0, ~2^-9 rel err)
#pragma unroll
        for (int icf = 0; icf < 4; ++icf)
#pragma unroll
            for (int rf = 0; rf < 2; ++rf)
#pragma unroll
                for (int j = 0; j < 4; ++j)
                    hacc[icf][rf][j] += bf16f(h0b[icf >> 1][rf][(icf & 1) * 4 + j]);

        // ---------------- head: dot(h, W_out) + b_out, tanh, store
        const float* wo = W_out + m * HID;
        const float bo = b_out[m];
#pragma unroll
        for (int rf = 0; rf < 2; ++rf) {
            float s = 0.f;
#pragma unroll
            for (int icf = 0; icf < 4; ++icf) {
                f32x4 wv = *(const f32x4*)(wo + icf * 16 + g * 4);
#pragma unroll
                for (int j = 0; j < 4; ++j)
                    s += hacc[icf][rf][j] * wv[j];
            }
            s += __shfl_xor(s, 16);
            s += __shfl_xor(s, 32);
            s += bo;
            float e = __expf(2.f * s);                 // overflow-safe tanh
            float o = 1.f - 2.f / (e + 1.f);
            if (g == 0)
                out[(size_t)(rowbase + rbase + rf * 16 + lrow) * NMODEL + m] = o;
        }
    }
}

extern "C" void kernel_launch(void* const* d_in, const int* in_sizes, int n_in,
                              void* d_out, int out_size, void* d_ws, size_t ws_size,
                              hipStream_t stream) {
    const float* x     = (const float*)d_in[0];
    const float* W_in  = (const float*)d_in[1];
    const float* b_in  = (const float*)d_in[2];
    const float* W_h   = (const float*)d_in[3];
    const float* b_h   = (const float*)d_in[4];
    const float* W_out = (const float*)d_in[5];
    const float* b_out = (const float*)d_in[6];
    float* out = (float*)d_out;

    short* wib = (short*)d_ws;                       // 24*64*64*8 bf16 = 1.5 MB
    short* whb = wib + NMODEL * 64 * HID * 8;        // 24*5*8*64*8 bf16 = 0.94 MB

    const int N = in_sizes[0] / DIN;                 // 65536

    dg_convert<<<3072, 256, 0, stream>>>(W_in, W_h, wib, whb);
    dg_main<<<N / 64, 512, 0, stream>>>(x, wib, whb, b_in, b_h, W_out, b_out, out);
}